// Round 3
// baseline (699.862 us; speedup 1.0000x reference)
//
#include <hip/hip_runtime.h>
#include <hip/hip_bf16.h>
#include <stdint.h>

// Problem constants
constexpr int CB  = 4;     // batch
constexpr int CS  = 2048;  // seq len
constexpr int CH  = 1024;  // hidden
constexpr int CNH = 16;    // heads
constexpr int CDH = 64;    // head dim
constexpr int CM  = CB * CS;  // 8192 rows

typedef __bf16 bf16x8 __attribute__((ext_vector_type(8)));
typedef float  f32x4  __attribute__((ext_vector_type(4)));

// round-to-nearest-even f32 -> bf16 (bit pattern)
__device__ __forceinline__ unsigned short f2bf(float f) {
    union { float f; unsigned u; } c; c.f = f;
    unsigned u = c.u;
    unsigned r = (u + 0x7fffu + ((u >> 16) & 1u)) >> 16;
    return (unsigned short)r;
}

// async global->LDS, 16B per lane. LDS dest = base + lane*16 (wave-uniform base).
__device__ __forceinline__ void gl_lds16(const void* g, void* l) {
    __builtin_amdgcn_global_load_lds((const __attribute__((address_space(1))) uint32_t*)g,
                                     (__attribute__((address_space(3))) uint32_t*)l,
                                     16, 0, 0);
}

__device__ __forceinline__ float fexp2(float x) {
#if __has_builtin(__builtin_amdgcn_exp2f)
    return __builtin_amdgcn_exp2f(x);
#else
    return exp2f(x);
#endif
}

// pack two f32 -> one dword of 2 bf16 (RNE). No builtin on gfx950 (m240) -> asm.
__device__ __forceinline__ unsigned cvtpk_bf16(float lo, float hi) {
    unsigned r;
    asm("v_cvt_pk_bf16_f32 %0, %1, %2" : "=v"(r) : "v"(lo), "v"(hi));
    return r;
}

// a' = [a_r0, a_r1, b_r0, b_r1]; b' = [a_r2, a_r3, b_r2, b_r3]  (16-lane rows)
__device__ __forceinline__ void pl32swap(unsigned &a, unsigned &b) {
#if __has_builtin(__builtin_amdgcn_permlane32_swap)
    auto r = __builtin_amdgcn_permlane32_swap(a, b, false, false);
    a = r[0]; b = r[1];
#else
    int lane = threadIdx.x & 63;
    unsigned as = (unsigned)__shfl((int)a, lane ^ 32);
    unsigned bs = (unsigned)__shfl((int)b, lane ^ 32);
    unsigned na = (lane < 32) ? a : bs;
    unsigned nb = (lane < 32) ? as : b;
    a = na; b = nb;
#endif
}

// a' = [a_r0, b_r0, a_r2, b_r2]; b' = [a_r1, b_r1, a_r3, b_r3]
__device__ __forceinline__ void pl16swap(unsigned &a, unsigned &b) {
#if __has_builtin(__builtin_amdgcn_permlane16_swap)
    auto r = __builtin_amdgcn_permlane16_swap(a, b, false, false);
    a = r[0]; b = r[1];
#else
    unsigned as = __builtin_amdgcn_ds_swizzle(a, 0x401F);  // lane ^ 16 within 32-halves
    unsigned bs = __builtin_amdgcn_ds_swizzle(b, 0x401F);
    int odd = (threadIdx.x >> 4) & 1;
    unsigned na = odd ? bs : a;
    unsigned nb = odd ? b : as;
    a = na; b = nb;
#endif
}

// 1/sqrt(dh) * log2(e): folded into Q at projection time
constexpr float C_SC = 0.125f * 1.44269504f;

// ---------------- fp32 -> bf16 convert (X + 3 weights, one launch) ----------------
__global__ __launch_bounds__(256) void cvt_all(const float* __restrict__ hs,
                                               const float* __restrict__ w0,
                                               const float* __restrict__ w1,
                                               const float* __restrict__ w2,
                                               unsigned short* __restrict__ Xb,
                                               unsigned short* __restrict__ Wb) {
    int z = blockIdx.y;
    const float* src; unsigned short* dst; int n4;
    if (z == 0)      { src = hs; dst = Xb;              n4 = CM * CH / 4; }
    else if (z == 1) { src = w0; dst = Wb;              n4 = CH * CH / 4; }
    else if (z == 2) { src = w1; dst = Wb + CH * CH;    n4 = CH * CH / 4; }
    else             { src = w2; dst = Wb + 2 * CH * CH; n4 = CH * CH / 4; }
    int i = blockIdx.x * blockDim.x + threadIdx.x;
    if (i < n4) {
        float4 v = ((const float4*)src)[i];
        ushort4 o;
        o.x = f2bf(v.x); o.y = f2bf(v.y); o.z = f2bf(v.z); o.w = f2bf(v.w);
        ((ushort4*)dst)[i] = o;
    }
}

// ---------------- fused QKV projection GEMM (pipelined + LDS-repacked epilogue) ----
// C[m,n] = sum_k X[m,k] * W[n,k] + bias[n]
// z=0 (Q): out [b,h,s,d], pre-scaled by C_SC. z=1 (K): [b,h,s,d]. z=2 (V): [b,h,d,s].
__global__ __launch_bounds__(256) void qkv_gemm(
    const unsigned short* __restrict__ Xb,
    const unsigned short* __restrict__ Wb,
    const float* __restrict__ bq, const float* __restrict__ bk, const float* __restrict__ bv,
    unsigned short* __restrict__ Qo,
    unsigned short* __restrict__ Ko,
    unsigned short* __restrict__ Vt)
{
    // staging (32 KB, double-buffered) and epilogue tile (34 KB) alias the same LDS
    __shared__ alignas(16) unsigned char smem[34816];
    typedef unsigned short (*tile_t)[128][32];
    tile_t As = (tile_t)smem;                 // [2][128][32]
    tile_t Bs = (tile_t)(smem + 16384);       // [2][128][32]
    typedef unsigned short (*ep_t)[136];      // [128][136] (pad -> 16B-aligned rows)
    ep_t Ep = (ep_t)smem;

    const int tid  = threadIdx.x;
    const int wave = tid >> 6, lane = tid & 63;
    const int wm = wave >> 1, wn = wave & 1;
    const int col = lane & 15, quad = lane >> 4;
    const int gm = blockIdx.x * 128, gn = blockIdx.y * 128;
    const int z  = blockIdx.z;
    const unsigned short* W = Wb + (size_t)z * CH * CH;

    f32x4 zero = {0.f, 0.f, 0.f, 0.f};
    f32x4 acc[4][4];
    for (int i = 0; i < 4; i++) for (int j = 0; j < 4; j++) acc[i][j] = zero;

    const int arow = lane >> 2;
    const int acol = (lane & 3) * 8;

    auto stage = [&](int buf, int k0) {
        for (int c = 0; c < 2; ++c) {
            int r0 = wave * 32 + c * 16;
            gl_lds16(Xb + (size_t)(gm + r0 + arow) * CH + k0 + acol, &As[buf][r0][0]);
            gl_lds16(W  + (size_t)(gn + r0 + arow) * CH + k0 + acol, &Bs[buf][r0][0]);
        }
    };

    stage(0, 0);
    for (int kk = 0; kk < 32; ++kk) {
        int cur = kk & 1;
        __syncthreads();
        if (kk < 31) stage(cur ^ 1, (kk + 1) * 32);
        bf16x8 af[4], bfm[4];
        for (int i = 0; i < 4; i++)
            af[i] = *(const bf16x8*)&As[cur][wm * 64 + i * 16 + col][quad * 8];
        for (int j = 0; j < 4; j++)
            bfm[j] = *(const bf16x8*)&Bs[cur][wn * 64 + j * 16 + col][quad * 8];
        for (int i = 0; i < 4; i++)
            for (int j = 0; j < 4; j++)
                acc[i][j] = __builtin_amdgcn_mfma_f32_16x16x32_bf16(af[i], bfm[j], acc[i][j], 0, 0, 0);
    }

    __syncthreads();   // staging buffers dead; reuse LDS for epilogue tile

    const float* bias = (z == 0) ? bq : (z == 1) ? bk : bv;
    const int bb = gm >> 11, ss0 = gm & 2047;
    const int h0 = gn >> 6;          // block's n-range spans 2 heads

    if (z == 2) {
        // transpose tile into Ep[n_local][m_local]; m-contiguous r-values pack as b32
        for (int j = 0; j < 4; j++) {
            int nl = wn * 64 + j * 16 + col;
            float bias_v = bias[gn + nl];
            for (int i = 0; i < 4; i++) {
                int ml = wm * 64 + i * 16 + quad * 4;
                unsigned d0 = (unsigned)f2bf(acc[i][j][0] + bias_v) |
                              ((unsigned)f2bf(acc[i][j][1] + bias_v) << 16);
                unsigned d1 = (unsigned)f2bf(acc[i][j][2] + bias_v) |
                              ((unsigned)f2bf(acc[i][j][3] + bias_v) << 16);
                *(unsigned*)&Ep[nl][ml]     = d0;
                *(unsigned*)&Ep[nl][ml + 2] = d1;
            }
        }
        __syncthreads();
        for (int p = 0; p < 8; p++) {
            int nl = p * 16 + (tid >> 4);
            int seg = tid & 15;
            uint4 v = *(const uint4*)&Ep[nl][seg * 8];
            int h = h0 + (nl >> 6), d = nl & 63;
            *(uint4*)(Vt + ((size_t)(bb * CNH + h) * CDH + d) * CS + ss0 + seg * 8) = v;
        }
    } else {
        const float mulf = (z == 0) ? C_SC : 1.0f;
        for (int j = 0; j < 4; j++) {
            int nl = wn * 64 + j * 16 + col;
            float bias_v = bias[gn + nl];
            for (int i = 0; i < 4; i++)
                for (int r = 0; r < 4; r++) {
                    int ml = wm * 64 + i * 16 + quad * 4 + r;
                    Ep[ml][nl] = f2bf((acc[i][j][r] + bias_v) * mulf);
                }
        }
        __syncthreads();
        unsigned short* dst01 = (z == 0) ? Qo : Ko;
        for (int p = 0; p < 8; p++) {
            int ml = p * 16 + (tid >> 4);
            int half2 = (tid >> 3) & 1, seg = tid & 7;
            uint4 v = *(const uint4*)&Ep[ml][half2 * 64 + seg * 8];
            int h = h0 + half2;
            *(uint4*)(dst01 + ((size_t)(bb * CNH + h) * CS + ss0 + ml) * CDH + seg * 8) = v;
        }
    }
}

// ---------------- flash attention v8: kv-split, 8 waves/block, 4 waves/SIMD --------
// grid: 512 blocks (8 q-blocks x 64 bh) x 512 threads. Wave w: q-group (w&3) of 64
// rows, kv-half (w>>2) of 1024 kv (16 tiles of 64). Static softmax (log2-domain, no
// running max) => kv-split partials combine by pure addition of O and l.
// Per-wave structure identical to v6 (64 q/wave, V frags hoisted, swapped QK^T,
// in-register P redistribute). Per-block staging = full K/V once (split, not dup).
// 2 blocks/CU (LDS 64.25 KB) -> 16 waves/CU = 4 waves/SIMD for latency hiding.
// XCD head-pinning: XCD c owns heads [8c, 8c+8); 8 heads x 512 KB K/V = 4 MB = L2.
// Post-loop: combine via LDS (aliases dead staging buffers), wave pairs (w, w^4).
__global__ __launch_bounds__(512, 4) void flash_attn(
    const unsigned short* __restrict__ Q,    // [B*h, S, d] (pre-scaled)
    const unsigned short* __restrict__ K,    // [B*h, S, d]
    const unsigned short* __restrict__ Vt,   // [B*h, d, S]
    const int* __restrict__ mask,            // [B, S]
    float* __restrict__ out)                 // [B, S, H]
{
    __shared__ alignas(16) unsigned char smem[65792];
    typedef unsigned short (*kv_t)[2][64][64];          // [half][buf][row][64]
    kv_t Ks = (kv_t)smem;                               // 32 KB
    kv_t Vs = (kv_t)(smem + 32768);                     // 32 KB  [half][buf][d][kv]
    unsigned int* Mbits = (unsigned int*)(smem + 65536);// 2048-bit mask (256 B)
    float* scr = (float*)smem;                          // combine scratch (aliases K/V)

    const int tid  = threadIdx.x;
    const int wave = tid >> 6, lane = tid & 63;
    const int col = lane & 15, quad = lane >> 4;
    const int qg  = wave & 3;        // q-group within block
    const int kvh = wave >> 2;       // kv half

    // XCD-aware bijective remap (512 wgs, 8 XCDs, launch order x-fastest)
    const int wg   = blockIdx.y * gridDim.x + blockIdx.x;
    const int nid  = (wg & 7) * 64 + (wg >> 3);
    const int bh   = nid >> 3;            // head index: XCD c gets heads [8c, 8c+8)
    const int qblk = nid & 7;
    const int bI = bh >> 4, hI = bh & 15;
    const int q0 = qblk * 256 + qg * 64;

    const unsigned short* Qp = Q  + (size_t)bh * CS * CDH;
    const unsigned short* Kp = K  + (size_t)bh * CS * CDH;
    const unsigned short* Vp = Vt + (size_t)bh * CDH * CS;

    // mask -> bitmask in LDS (first loop barrier publishes it)
    {
        const int* mg = mask + bI * CS;
        for (int j = 0; j < 4; j++) {
            int idx = wave * 256 + j * 64 + lane;
            unsigned long long bal = __ballot(mg[idx] != 0);
            if (lane == 0) {
                Mbits[(wave * 4 + j) * 2]     = (unsigned int)bal;
                Mbits[(wave * 4 + j) * 2 + 1] = (unsigned int)(bal >> 32);
            }
        }
    }

    // Q fragments in registers: frag[n=col][k=quad*8+j], 64 q rows per wave
    bf16x8 aq[4][2];
    for (int i = 0; i < 4; i++)
        for (int ks = 0; ks < 2; ks++)
            aq[i][ks] = *(const bf16x8*)(Qp + (size_t)(q0 + i * 16 + col) * CDH + ks * 32 + quad * 8);

    bf16x8 onesb;
    {
        union { unsigned short u; __bf16 b; } ob; ob.u = 0x3F80;  // bf16 1.0
        for (int j = 0; j < 8; j++) onesb[j] = ob.b;
    }

    f32x4 zero = {0.f, 0.f, 0.f, 0.f};
    f32x4 o[4][4], lfr[4];
    for (int i = 0; i < 4; i++) {
        lfr[i] = zero;
        for (int id = 0; id < 4; id++) o[i][id] = zero;
    }

    const int srow = lane >> 3;
    const int schk = (lane & 7) ^ srow;      // swizzled global chunk index

    // stage one 64x64 K tile + 64x64 V tile for this wave's kv-half.
    // 4 waves per half (qg 0..3) x 2 c-steps x 8 rows = 64 rows each of K and V.
    auto stageKV = [&](int buf, int t) {
        int gt = kvh * 16 + t;               // global kv tile
        const unsigned short* kg = Kp + (size_t)gt * 64 * CDH;
        for (int c = 0; c < 2; c++) {
            int r0 = qg * 16 + c * 8;
            gl_lds16(kg + (size_t)(r0 + srow) * CDH + schk * 8, &Ks[kvh][buf][r0][0]);
            gl_lds16(Vp + (size_t)(r0 + srow) * CS + gt * 64 + schk * 8, &Vs[kvh][buf][r0][0]);
        }
    };

    stageKV(0, 0);
    for (int kt = 0; kt < 16; ++kt) {
        int cur = kt & 1;
        __syncthreads();
        if (kt < 15) stageKV(cur ^ 1, kt + 1);

        // S'^T = (K Q^T) (log2-domain): sfr[i][ik][r] = S'[q=i*16+col][kv=ik*16+quad*4+r]
        f32x4 sfr[4][4];
        for (int i = 0; i < 4; i++) for (int ik = 0; ik < 4; ik++) sfr[i][ik] = zero;
        for (int ks = 0; ks < 2; ks++) {
            bf16x8 bkf[4];
            for (int ik = 0; ik < 4; ik++)
                bkf[ik] = *(const bf16x8*)&Ks[kvh][cur][ik * 16 + col][((ks * 4 + quad) ^ (col & 7)) * 8];
            __builtin_amdgcn_s_setprio(1);
            for (int i = 0; i < 4; i++)
                for (int ik = 0; ik < 4; ik++)
                    sfr[i][ik] = __builtin_amdgcn_mfma_f32_16x16x32_bf16(bkf[ik], aq[i][ks], sfr[i][ik], 0, 0, 0);
            __builtin_amdgcn_s_setprio(0);
        }

        // mask add only if some kv masked (uniform branch; all-ones in practice)
        int gt = kvh * 16 + kt;
        unsigned int w0 = Mbits[gt * 2], w1 = Mbits[gt * 2 + 1];
        if ((w0 & w1) != 0xFFFFFFFFu) {
            for (int ik = 0; ik < 4; ik++)
                for (int r = 0; r < 4; r++) {
                    int kv = ik * 16 + quad * 4 + r;
                    unsigned bit = (kv < 32) ? (w0 >> kv) : (w1 >> (kv - 32));
                    float madd = (bit & 1u) ? 0.f : -1.0e30f;
                    for (int i = 0; i < 4; i++) sfr[i][ik][r] += madd;
                }
        }

        // V fragments hoisted (i-invariant): frag[n=col -> d][k=quad*8+j -> kv]
        bf16x8 bvf[2][4];
        for (int ks = 0; ks < 2; ks++)
            for (int id = 0; id < 4; id++)
                bvf[ks][id] = *(const bf16x8*)&Vs[kvh][cur][id * 16 + col][((ks * 4 + quad) ^ (col & 7)) * 8];

        // P = 2^(s'); pack to bf16 pairs, redistribute in-register into PV A-frags.
        for (int i = 0; i < 4; i++) {
            unsigned c[4][2];
            for (int ik = 0; ik < 4; ik++)
                for (int h = 0; h < 2; h++)
                    c[ik][h] = cvtpk_bf16(fexp2(sfr[i][ik][2 * h]), fexp2(sfr[i][ik][2 * h + 1]));

            unsigned a0 = c[0][0], b0 = c[1][0]; pl32swap(a0, b0); pl16swap(a0, b0); // ap0.dw0, ap0.dw2
            unsigned a1 = c[0][1], b1 = c[1][1]; pl32swap(a1, b1); pl16swap(a1, b1); // ap0.dw1, ap0.dw3
            unsigned a2 = c[2][0], b2 = c[3][0]; pl32swap(a2, b2); pl16swap(a2, b2); // ap1.dw0, ap1.dw2
            unsigned a3 = c[2][1], b3 = c[3][1]; pl32swap(a3, b3); pl16swap(a3, b3); // ap1.dw1, ap1.dw3

            uint4 lo4; lo4.x = a0; lo4.y = a1; lo4.z = b0; lo4.w = b1;
            uint4 hi4; hi4.x = a2; hi4.y = a3; hi4.z = b2; hi4.w = b3;
            bf16x8 ap0, ap1;
            __builtin_memcpy(&ap0, &lo4, 16);
            __builtin_memcpy(&ap1, &hi4, 16);

            __builtin_amdgcn_s_setprio(1);
            for (int id = 0; id < 4; id++)
                o[i][id] = __builtin_amdgcn_mfma_f32_16x16x32_bf16(ap0, bvf[0][id], o[i][id], 0, 0, 0);
            lfr[i] = __builtin_amdgcn_mfma_f32_16x16x32_bf16(ap0, onesb, lfr[i], 0, 0, 0);
            for (int id = 0; id < 4; id++)
                o[i][id] = __builtin_amdgcn_mfma_f32_16x16x32_bf16(ap1, bvf[1][id], o[i][id], 0, 0, 0);
            lfr[i] = __builtin_amdgcn_mfma_f32_16x16x32_bf16(ap1, onesb, lfr[i], 0, 0, 0);
            __builtin_amdgcn_s_setprio(0);
        }
    }

    // ---- combine kv-halves (wave pairs w, w^4), then epilogue -------------------
    // half0 owns id {0,1}; half1 owns id {2,3}. Static softmax => plain sums.
    __syncthreads();                          // staging LDS dead from here
    const int ownb = kvh * 2;                 // owned id base
    const int notb = 2 - ownb;                // not-owned id base
    const int pw   = wave ^ 4;

    // Round A: exchange not-owned O halves (8 KB/wave, 64 KB total = exactly scr)
    for (int i = 0; i < 4; i++)
        for (int j2 = 0; j2 < 2; j2++)
            *(f32x4*)&scr[(((wave * 4 + i) * 2 + j2) * 64 + lane) * 4] = o[i][notb + j2];
    __syncthreads();
    for (int i = 0; i < 4; i++)
        for (int j2 = 0; j2 < 2; j2++) {
            f32x4 p = *(const f32x4*)&scr[(((pw * 4 + i) * 2 + j2) * 64 + lane) * 4];
            o[i][ownb + j2] += p;
        }
    __syncthreads();
    // Round B: exchange lfr (4 KB/wave)
    for (int i = 0; i < 4; i++)
        *(f32x4*)&scr[((wave * 4 + i) * 64 + lane) * 4] = lfr[i];
    __syncthreads();
    for (int i = 0; i < 4; i++) {
        f32x4 p = *(const f32x4*)&scr[((pw * 4 + i) * 64 + lane) * 4];
        lfr[i] += p;
    }

    // epilogue: each wave stores its 2 owned d-groups for its 64 q rows
    for (int i = 0; i < 4; i++)
        for (int r = 0; r < 4; r++) {
            int sI = q0 + i * 16 + quad * 4 + r;
            float inv = 1.0f / lfr[i][r];
            for (int j2 = 0; j2 < 2; j2++) {
                int id = ownb + j2;
                out[((size_t)(bI * CS + sI)) * CH + hI * CDH + id * 16 + col] = o[i][id][r] * inv;
            }
        }
}

extern "C" void kernel_launch(void* const* d_in, const int* in_sizes, int n_in,
                              void* d_out, int out_size, void* d_ws, size_t ws_size,
                              hipStream_t stream) {
    const float* hs  = (const float*)d_in[0];
    const int*  mask = (const int*)d_in[1];
    const float* Wq  = (const float*)d_in[2];
    const float* bq  = (const float*)d_in[3];
    const float* Wk  = (const float*)d_in[4];
    const float* bk  = (const float*)d_in[5];
    const float* Wv  = (const float*)d_in[6];
    const float* bv  = (const float*)d_in[7];
    float* out = (float*)d_out;

    char* ws = (char*)d_ws;
    unsigned short* Xb = (unsigned short*)(ws);                    // 16 MB
    unsigned short* Wb = (unsigned short*)(ws + 16777216);         // 6 MB
    unsigned short* Qb = (unsigned short*)(ws + 23068672);         // 16 MB
    unsigned short* Kb = (unsigned short*)(ws + 39845888);         // 16 MB
    unsigned short* Vt = (unsigned short*)(ws + 56623104);         // 16 MB

    cvt_all<<<dim3(8192, 4), 256, 0, stream>>>(hs, Wq, Wk, Wv, Xb, Wb);

    qkv_gemm<<<dim3(CM / 128, CH / 128, 3), 256, 0, stream>>>(Xb, Wb, bq, bk, bv, Qb, Kb, Vt);

    flash_attn<<<dim3(8, 64), 512, 0, stream>>>(Qb, Kb, Vt, mask, out);
}

// Round 4
// 250.785 us; speedup vs baseline: 2.7907x; 2.7907x over previous
//
#include <hip/hip_runtime.h>
#include <hip/hip_bf16.h>
#include <stdint.h>

// Problem constants
constexpr int CB  = 4;     // batch
constexpr int CS  = 2048;  // seq len
constexpr int CH  = 1024;  // hidden
constexpr int CNH = 16;    // heads
constexpr int CDH = 64;    // head dim
constexpr int CM  = CB * CS;  // 8192 rows

typedef __bf16 bf16x8 __attribute__((ext_vector_type(8)));
typedef float  f32x4  __attribute__((ext_vector_type(4)));

// round-to-nearest-even f32 -> bf16 (bit pattern)
__device__ __forceinline__ unsigned short f2bf(float f) {
    union { float f; unsigned u; } c; c.f = f;
    unsigned u = c.u;
    unsigned r = (u + 0x7fffu + ((u >> 16) & 1u)) >> 16;
    return (unsigned short)r;
}

// async global->LDS, 16B per lane. LDS dest = base + lane*16 (wave-uniform base).
__device__ __forceinline__ void gl_lds16(const void* g, void* l) {
    __builtin_amdgcn_global_load_lds((const __attribute__((address_space(1))) uint32_t*)g,
                                     (__attribute__((address_space(3))) uint32_t*)l,
                                     16, 0, 0);
}

__device__ __forceinline__ float fexp2(float x) {
#if __has_builtin(__builtin_amdgcn_exp2f)
    return __builtin_amdgcn_exp2f(x);
#else
    return exp2f(x);
#endif
}

// pack two f32 -> one dword of 2 bf16 (RNE). No builtin on gfx950 (m240) -> asm.
__device__ __forceinline__ unsigned cvtpk_bf16(float lo, float hi) {
    unsigned r;
    asm("v_cvt_pk_bf16_f32 %0, %1, %2" : "=v"(r) : "v"(lo), "v"(hi));
    return r;
}

// a' = [a_r0, a_r1, b_r0, b_r1]; b' = [a_r2, a_r3, b_r2, b_r3]  (16-lane rows)
__device__ __forceinline__ void pl32swap(unsigned &a, unsigned &b) {
#if __has_builtin(__builtin_amdgcn_permlane32_swap)
    auto r = __builtin_amdgcn_permlane32_swap(a, b, false, false);
    a = r[0]; b = r[1];
#else
    int lane = threadIdx.x & 63;
    unsigned as = (unsigned)__shfl((int)a, lane ^ 32);
    unsigned bs = (unsigned)__shfl((int)b, lane ^ 32);
    unsigned na = (lane < 32) ? a : bs;
    unsigned nb = (lane < 32) ? as : b;
    a = na; b = nb;
#endif
}

// a' = [a_r0, b_r0, a_r2, b_r2]; b' = [a_r1, b_r1, a_r3, b_r3]
__device__ __forceinline__ void pl16swap(unsigned &a, unsigned &b) {
#if __has_builtin(__builtin_amdgcn_permlane16_swap)
    auto r = __builtin_amdgcn_permlane16_swap(a, b, false, false);
    a = r[0]; b = r[1];
#else
    unsigned as = __builtin_amdgcn_ds_swizzle(a, 0x401F);  // lane ^ 16 within 32-halves
    unsigned bs = __builtin_amdgcn_ds_swizzle(b, 0x401F);
    int odd = (threadIdx.x >> 4) & 1;
    unsigned na = odd ? bs : a;
    unsigned nb = odd ? b : as;
    a = na; b = nb;
#endif
}

// 1/sqrt(dh) * log2(e): folded into Q at projection time
constexpr float C_SC = 0.125f * 1.44269504f;

// ---------------- fp32 -> bf16 convert (X + 3 weights, one launch) ----------------
__global__ __launch_bounds__(256) void cvt_all(const float* __restrict__ hs,
                                               const float* __restrict__ w0,
                                               const float* __restrict__ w1,
                                               const float* __restrict__ w2,
                                               unsigned short* __restrict__ Xb,
                                               unsigned short* __restrict__ Wb) {
    int z = blockIdx.y;
    const float* src; unsigned short* dst; int n4;
    if (z == 0)      { src = hs; dst = Xb;              n4 = CM * CH / 4; }
    else if (z == 1) { src = w0; dst = Wb;              n4 = CH * CH / 4; }
    else if (z == 2) { src = w1; dst = Wb + CH * CH;    n4 = CH * CH / 4; }
    else             { src = w2; dst = Wb + 2 * CH * CH; n4 = CH * CH / 4; }
    int i = blockIdx.x * blockDim.x + threadIdx.x;
    if (i < n4) {
        float4 v = ((const float4*)src)[i];
        ushort4 o;
        o.x = f2bf(v.x); o.y = f2bf(v.y); o.z = f2bf(v.z); o.w = f2bf(v.w);
        ((ushort4*)dst)[i] = o;
    }
}

// ---------------- fused QKV projection GEMM (pipelined + LDS-repacked epilogue) ----
// C[m,n] = sum_k X[m,k] * W[n,k] + bias[n]
// z=0 (Q): out [b,h,s,d], pre-scaled by C_SC. z=1 (K): [b,h,s,d]. z=2 (V): [b,h,d,s].
__global__ __launch_bounds__(256) void qkv_gemm(
    const unsigned short* __restrict__ Xb,
    const unsigned short* __restrict__ Wb,
    const float* __restrict__ bq, const float* __restrict__ bk, const float* __restrict__ bv,
    unsigned short* __restrict__ Qo,
    unsigned short* __restrict__ Ko,
    unsigned short* __restrict__ Vt)
{
    // staging (32 KB, double-buffered) and epilogue tile (34 KB) alias the same LDS
    __shared__ alignas(16) unsigned char smem[34816];
    typedef unsigned short (*tile_t)[128][32];
    tile_t As = (tile_t)smem;                 // [2][128][32]
    tile_t Bs = (tile_t)(smem + 16384);       // [2][128][32]
    typedef unsigned short (*ep_t)[136];      // [128][136] (pad -> 16B-aligned rows)
    ep_t Ep = (ep_t)smem;

    const int tid  = threadIdx.x;
    const int wave = tid >> 6, lane = tid & 63;
    const int wm = wave >> 1, wn = wave & 1;
    const int col = lane & 15, quad = lane >> 4;
    const int gm = blockIdx.x * 128, gn = blockIdx.y * 128;
    const int z  = blockIdx.z;
    const unsigned short* W = Wb + (size_t)z * CH * CH;

    f32x4 zero = {0.f, 0.f, 0.f, 0.f};
    f32x4 acc[4][4];
    for (int i = 0; i < 4; i++) for (int j = 0; j < 4; j++) acc[i][j] = zero;

    const int arow = lane >> 2;
    const int acol = (lane & 3) * 8;

    auto stage = [&](int buf, int k0) {
        for (int c = 0; c < 2; ++c) {
            int r0 = wave * 32 + c * 16;
            gl_lds16(Xb + (size_t)(gm + r0 + arow) * CH + k0 + acol, &As[buf][r0][0]);
            gl_lds16(W  + (size_t)(gn + r0 + arow) * CH + k0 + acol, &Bs[buf][r0][0]);
        }
    };

    stage(0, 0);
    for (int kk = 0; kk < 32; ++kk) {
        int cur = kk & 1;
        __syncthreads();
        if (kk < 31) stage(cur ^ 1, (kk + 1) * 32);
        bf16x8 af[4], bfm[4];
        for (int i = 0; i < 4; i++)
            af[i] = *(const bf16x8*)&As[cur][wm * 64 + i * 16 + col][quad * 8];
        for (int j = 0; j < 4; j++)
            bfm[j] = *(const bf16x8*)&Bs[cur][wn * 64 + j * 16 + col][quad * 8];
        for (int i = 0; i < 4; i++)
            for (int j = 0; j < 4; j++)
                acc[i][j] = __builtin_amdgcn_mfma_f32_16x16x32_bf16(af[i], bfm[j], acc[i][j], 0, 0, 0);
    }

    __syncthreads();   // staging buffers dead; reuse LDS for epilogue tile

    const float* bias = (z == 0) ? bq : (z == 1) ? bk : bv;
    const int bb = gm >> 11, ss0 = gm & 2047;
    const int h0 = gn >> 6;          // block's n-range spans 2 heads

    if (z == 2) {
        // transpose tile into Ep[n_local][m_local]; m-contiguous r-values pack as b32
        for (int j = 0; j < 4; j++) {
            int nl = wn * 64 + j * 16 + col;
            float bias_v = bias[gn + nl];
            for (int i = 0; i < 4; i++) {
                int ml = wm * 64 + i * 16 + quad * 4;
                unsigned d0 = (unsigned)f2bf(acc[i][j][0] + bias_v) |
                              ((unsigned)f2bf(acc[i][j][1] + bias_v) << 16);
                unsigned d1 = (unsigned)f2bf(acc[i][j][2] + bias_v) |
                              ((unsigned)f2bf(acc[i][j][3] + bias_v) << 16);
                *(unsigned*)&Ep[nl][ml]     = d0;
                *(unsigned*)&Ep[nl][ml + 2] = d1;
            }
        }
        __syncthreads();
        for (int p = 0; p < 8; p++) {
            int nl = p * 16 + (tid >> 4);
            int seg = tid & 15;
            uint4 v = *(const uint4*)&Ep[nl][seg * 8];
            int h = h0 + (nl >> 6), d = nl & 63;
            *(uint4*)(Vt + ((size_t)(bb * CNH + h) * CDH + d) * CS + ss0 + seg * 8) = v;
        }
    } else {
        const float mulf = (z == 0) ? C_SC : 1.0f;
        for (int j = 0; j < 4; j++) {
            int nl = wn * 64 + j * 16 + col;
            float bias_v = bias[gn + nl];
            for (int i = 0; i < 4; i++)
                for (int r = 0; r < 4; r++) {
                    int ml = wm * 64 + i * 16 + quad * 4 + r;
                    Ep[ml][nl] = f2bf((acc[i][j][r] + bias_v) * mulf);
                }
        }
        __syncthreads();
        unsigned short* dst01 = (z == 0) ? Qo : Ko;
        for (int p = 0; p < 8; p++) {
            int ml = p * 16 + (tid >> 4);
            int half2 = (tid >> 3) & 1, seg = tid & 7;
            uint4 v = *(const uint4*)&Ep[ml][half2 * 64 + seg * 8];
            int h = h0 + half2;
            *(uint4*)(dst01 + ((size_t)(bb * CNH + h) * CS + ss0 + ml) * CDH + seg * 8) = v;
        }
    }
}

// ---------------- flash attention v9: v6 shape + XCD head-pin + counted vmcnt ------
// grid: 512 blocks (8 q-blocks x 64 bh) x 256 threads = 4 waves x 64 q rows.
// 2 blocks/CU (grid-limited); per-wave state ~200 regs (incl acc) => 2 waves/SIMD is
// structural (4 waves needs <=128 total: R3 spilled catastrophically). So overlap
// comes from ILP: triple-buffered K/V staging with counted s_waitcnt vmcnt(4) and a
// single raw s_barrier per iter -- batch t+1 stays in flight across the barrier
// (T4; never drain to 0 in-loop). XCD head-pinning (R2-proven: FETCH 139->29 MB):
// XCD c owns heads [8c,8c+8), 8 x 512 KB K/V = 4 MB = its L2.
// Swapped QK^T + in-register P redistribute (cvt_pk + permlane), static softmax
// (log2-domain, Q pre-scaled), V frags hoisted, XOR-swizzled LDS, setprio on MFMA.
__global__ __launch_bounds__(256, 2) void flash_attn(
    const unsigned short* __restrict__ Q,    // [B*h, S, d] (pre-scaled)
    const unsigned short* __restrict__ K,    // [B*h, S, d]
    const unsigned short* __restrict__ Vt,   // [B*h, d, S]
    const int* __restrict__ mask,            // [B, S]
    float* __restrict__ out)                 // [B, S, H]
{
    __shared__ alignas(16) unsigned short Ks[3][64][64];   // 24 KB, triple-buffered
    __shared__ alignas(16) unsigned short Vs[3][64][64];   // 24 KB, [d][kv]
    __shared__ unsigned int Mbits[64];                     // 2048-bit mask

    const int tid  = threadIdx.x;
    const int wave = tid >> 6, lane = tid & 63;
    const int col = lane & 15, quad = lane >> 4;

    // XCD-aware bijective remap (512 wgs, 8 XCDs, launch order x-fastest)
    const int wg   = blockIdx.y * gridDim.x + blockIdx.x;
    const int nid  = (wg & 7) * 64 + (wg >> 3);
    const int bh   = nid >> 3;            // head index: XCD c gets heads [8c, 8c+8)
    const int qblk = nid & 7;
    const int bI = bh >> 4, hI = bh & 15;
    const int q0 = qblk * 256 + wave * 64;

    const unsigned short* Qp = Q  + (size_t)bh * CS * CDH;
    const unsigned short* Kp = K  + (size_t)bh * CS * CDH;
    const unsigned short* Vp = Vt + (size_t)bh * CDH * CS;

    // mask -> bitmask in LDS (drained below; first loop barrier publishes it)
    {
        const int* mg = mask + bI * CS;
        for (int j = 0; j < 8; j++) {
            int idx = wave * 512 + j * 64 + lane;
            unsigned long long bal = __ballot(mg[idx] != 0);
            if (lane == 0) {
                Mbits[wave * 16 + j * 2]     = (unsigned int)bal;
                Mbits[wave * 16 + j * 2 + 1] = (unsigned int)(bal >> 32);
            }
        }
    }

    // Q fragments in registers: frag[n=col][k=quad*8+j], 64 q rows per wave
    bf16x8 aq[4][2];
    for (int i = 0; i < 4; i++)
        for (int ks = 0; ks < 2; ks++)
            aq[i][ks] = *(const bf16x8*)(Qp + (size_t)(q0 + i * 16 + col) * CDH + ks * 32 + quad * 8);

    bf16x8 onesb;
    {
        union { unsigned short u; __bf16 b; } ob; ob.u = 0x3F80;  // bf16 1.0
        for (int j = 0; j < 8; j++) onesb[j] = ob.b;
    }

    f32x4 zero = {0.f, 0.f, 0.f, 0.f};
    f32x4 o[4][4], lfr[4];
    for (int i = 0; i < 4; i++) {
        lfr[i] = zero;
        for (int id = 0; id < 4; id++) o[i][id] = zero;
    }

    const int srow = lane >> 3;
    const int schk = (lane & 7) ^ srow;      // swizzled global chunk index

    // one stage call = 4 gl_lds per wave (2 c-steps x {K,V}); waves cover 64 rows
    auto stageKV = [&](int buf, int t) {
        const unsigned short* kg = Kp + (size_t)t * 64 * CDH;
        for (int c = 0; c < 2; c++) {
            int r0 = wave * 16 + c * 8;
            gl_lds16(kg + (size_t)(r0 + srow) * CDH + schk * 8, &Ks[buf][r0][0]);
            gl_lds16(Vp + (size_t)(r0 + srow) * CS + t * 64 + schk * 8, &Vs[buf][r0][0]);
        }
    };

    // prologue: 2 tiles in flight; drain LDS queue so Mbits publish at first barrier
    stageKV(0, 0);
    stageKV(1, 1);
    asm volatile("s_waitcnt lgkmcnt(0)" ::: "memory");

    int cur = 0, sp = 2;
    for (int kt = 0; kt < 32; ++kt) {
        // batch kt done (4 newest = batch kt+1 stay in flight); last iter drains all
        if (kt < 31) asm volatile("s_waitcnt vmcnt(4)" ::: "memory");
        else         asm volatile("s_waitcnt vmcnt(0)" ::: "memory");
        asm volatile("s_barrier" ::: "memory");
        if (kt < 30) stageKV(sp, kt + 2);   // overwrites buffer last read at kt-1

        // S'^T = (K Q^T) (log2-domain): sfr[i][ik][r] = S'[q=i*16+col][kv=ik*16+quad*4+r]
        f32x4 sfr[4][4];
        for (int i = 0; i < 4; i++) for (int ik = 0; ik < 4; ik++) sfr[i][ik] = zero;
        for (int ks = 0; ks < 2; ks++) {
            bf16x8 bkf[4];
            for (int ik = 0; ik < 4; ik++)
                bkf[ik] = *(const bf16x8*)&Ks[cur][ik * 16 + col][((ks * 4 + quad) ^ (col & 7)) * 8];
            __builtin_amdgcn_s_setprio(1);
            for (int i = 0; i < 4; i++)
                for (int ik = 0; ik < 4; ik++)
                    sfr[i][ik] = __builtin_amdgcn_mfma_f32_16x16x32_bf16(bkf[ik], aq[i][ks], sfr[i][ik], 0, 0, 0);
            __builtin_amdgcn_s_setprio(0);
        }

        // mask add only if some kv masked (uniform branch; all-ones in practice)
        unsigned int w0 = Mbits[kt * 2], w1 = Mbits[kt * 2 + 1];
        if ((w0 & w1) != 0xFFFFFFFFu) {
            for (int ik = 0; ik < 4; ik++)
                for (int r = 0; r < 4; r++) {
                    int kv = ik * 16 + quad * 4 + r;
                    unsigned bit = (kv < 32) ? (w0 >> kv) : (w1 >> (kv - 32));
                    float madd = (bit & 1u) ? 0.f : -1.0e30f;
                    for (int i = 0; i < 4; i++) sfr[i][ik][r] += madd;
                }
        }

        // V fragments hoisted (i-invariant): frag[n=col -> d][k=quad*8+j -> kv]
        bf16x8 bvf[2][4];
        for (int ks = 0; ks < 2; ks++)
            for (int id = 0; id < 4; id++)
                bvf[ks][id] = *(const bf16x8*)&Vs[cur][id * 16 + col][((ks * 4 + quad) ^ (col & 7)) * 8];

        // P = 2^(s'); pack to bf16 pairs, redistribute in-register into PV A-frags.
        for (int i = 0; i < 4; i++) {
            unsigned c[4][2];
            for (int ik = 0; ik < 4; ik++)
                for (int h = 0; h < 2; h++)
                    c[ik][h] = cvtpk_bf16(fexp2(sfr[i][ik][2 * h]), fexp2(sfr[i][ik][2 * h + 1]));

            unsigned a0 = c[0][0], b0 = c[1][0]; pl32swap(a0, b0); pl16swap(a0, b0); // ap0.dw0, ap0.dw2
            unsigned a1 = c[0][1], b1 = c[1][1]; pl32swap(a1, b1); pl16swap(a1, b1); // ap0.dw1, ap0.dw3
            unsigned a2 = c[2][0], b2 = c[3][0]; pl32swap(a2, b2); pl16swap(a2, b2); // ap1.dw0, ap1.dw2
            unsigned a3 = c[2][1], b3 = c[3][1]; pl32swap(a3, b3); pl16swap(a3, b3); // ap1.dw1, ap1.dw3

            uint4 lo4; lo4.x = a0; lo4.y = a1; lo4.z = b0; lo4.w = b1;
            uint4 hi4; hi4.x = a2; hi4.y = a3; hi4.z = b2; hi4.w = b3;
            bf16x8 ap0, ap1;
            __builtin_memcpy(&ap0, &lo4, 16);
            __builtin_memcpy(&ap1, &hi4, 16);

            __builtin_amdgcn_s_setprio(1);
            for (int id = 0; id < 4; id++)
                o[i][id] = __builtin_amdgcn_mfma_f32_16x16x32_bf16(ap0, bvf[0][id], o[i][id], 0, 0, 0);
            lfr[i] = __builtin_amdgcn_mfma_f32_16x16x32_bf16(ap0, onesb, lfr[i], 0, 0, 0);
            for (int id = 0; id < 4; id++)
                o[i][id] = __builtin_amdgcn_mfma_f32_16x16x32_bf16(ap1, bvf[1][id], o[i][id], 0, 0, 0);
            lfr[i] = __builtin_amdgcn_mfma_f32_16x16x32_bf16(ap1, onesb, lfr[i], 0, 0, 0);
            __builtin_amdgcn_s_setprio(0);
        }

        cur = (cur + 1 == 3) ? 0 : cur + 1;
        sp  = (sp  + 1 == 3) ? 0 : sp  + 1;
    }

    // epilogue: out[b][s][h*64+d] = O / l
    for (int i = 0; i < 4; i++)
        for (int r = 0; r < 4; r++) {
            int sI = q0 + i * 16 + quad * 4 + r;
            float inv = 1.0f / lfr[i][r];
            for (int id = 0; id < 4; id++)
                out[((size_t)(bI * CS + sI)) * CH + hI * CDH + id * 16 + col] = o[i][id][r] * inv;
        }
}

extern "C" void kernel_launch(void* const* d_in, const int* in_sizes, int n_in,
                              void* d_out, int out_size, void* d_ws, size_t ws_size,
                              hipStream_t stream) {
    const float* hs  = (const float*)d_in[0];
    const int*  mask = (const int*)d_in[1];
    const float* Wq  = (const float*)d_in[2];
    const float* bq  = (const float*)d_in[3];
    const float* Wk  = (const float*)d_in[4];
    const float* bk  = (const float*)d_in[5];
    const float* Wv  = (const float*)d_in[6];
    const float* bv  = (const float*)d_in[7];
    float* out = (float*)d_out;

    char* ws = (char*)d_ws;
    unsigned short* Xb = (unsigned short*)(ws);                    // 16 MB
    unsigned short* Wb = (unsigned short*)(ws + 16777216);         // 6 MB
    unsigned short* Qb = (unsigned short*)(ws + 23068672);         // 16 MB
    unsigned short* Kb = (unsigned short*)(ws + 39845888);         // 16 MB
    unsigned short* Vt = (unsigned short*)(ws + 56623104);         // 16 MB

    cvt_all<<<dim3(8192, 4), 256, 0, stream>>>(hs, Wq, Wk, Wv, Xb, Wb);

    qkv_gemm<<<dim3(CM / 128, CH / 128, 3), 256, 0, stream>>>(Xb, Wb, bq, bk, bv, Qb, Kb, Vt);

    flash_attn<<<dim3(8, 64), 256, 0, stream>>>(Qb, Kb, Vt, mask, out);
}